// Round 12
// baseline (664.830 us; speedup 1.0000x reference)
//
#include <hip/hip_runtime.h>

#define NROWS 8192
#define DIM   1024
#define K3    3072
#define NLAYERS 4

typedef unsigned short u16;
typedef __attribute__((ext_vector_type(8))) __bf16 bf16x8;
typedef __attribute__((ext_vector_type(8))) unsigned short u16x8;
typedef __attribute__((ext_vector_type(4))) float  f32x4;

__device__ __forceinline__ u16 f2bf(float f) {
  unsigned u = __builtin_bit_cast(unsigned, f);
  u += 0x7FFFu + ((u >> 16) & 1u);   // round-to-nearest-even to bf16
  return (u16)(u >> 16);
}
__device__ __forceinline__ float bf2f(u16 h) {
  unsigned u = ((unsigned)h) << 16;
  return __builtin_bit_cast(float, u);
}

__device__ __forceinline__ void gload16(const void* g, void* l) {
  __builtin_amdgcn_global_load_lds((__attribute__((address_space(1))) void*)g,
                                   (__attribute__((address_space(3))) void*)l,
                                   16, 0, 0);
}

// Blocked (k-chunk-major) layouts, kc = k>>3:
//   X  : [128 kc][8192 row][8]   elem (row,k) at kc*NROWS*8 + row*8 + (k&7)
//   WT : [384 kc][1024 col][8]   elem (col,kk) at kc*DIM*8 + col*8 + (kk&7)
//   oob: linear [1024] (== [128 kc][8])

// ---------------------------------------------------------------------------
// W [L][3072][1024] f32 -> WT_hi/lo blocked bf16 split.
// Thread per (kc, n): 8 coalesced 256B reads, one coalesced u16x8 write each.
// ---------------------------------------------------------------------------
__global__ void k_prep_w(const float* __restrict__ Ws,
                         u16* __restrict__ WThi, u16* __restrict__ WTlo) {
  const int L   = blockIdx.y;
  const int idx = blockIdx.x * 256 + threadIdx.x;   // 0 .. K3/8*DIM-1
  const int kc = idx >> 10;           // k-chunk 0..383
  const int n  = idx & 1023;          // output col (lane-consecutive)
  const size_t src = (size_t)L * K3 * DIM + (size_t)kc * 8 * DIM + n;
  u16x8 H, Lv;
#pragma unroll
  for (int e = 0; e < 8; ++e) {
    const float v = Ws[src + (size_t)e * DIM];      // 64 lanes x 4B contiguous
    const u16 h = f2bf(v);
    H[e]  = h;
    Lv[e] = f2bf(v - bf2f(h));
  }
  const size_t dst = (size_t)L * K3 * DIM + (size_t)kc * (DIM * 8) + (size_t)n * 8;
  *reinterpret_cast<u16x8*>(WThi + dst) = H;        // 64 lanes x 16B contiguous
  *reinterpret_cast<u16x8*>(WTlo + dst) = Lv;
}

__global__ void k_oob(const float* __restrict__ oob, u16* __restrict__ hi,
                      u16* __restrict__ lo) {
  const int i = blockIdx.x * 256 + threadIdx.x;
  if (i < DIM) {
    const float v = oob[i];
    const u16 h = f2bf(v);
    hi[i] = h;
    lo[i] = f2bf(v - bf2f(h));
  }
}

// X f32 [8192][1024] -> blocked split pair (writes coalesced over row).
__global__ void k_split(const float* __restrict__ X, u16* __restrict__ hi,
                        u16* __restrict__ lo) {
  const int idx = blockIdx.x * 256 + threadIdx.x;   // 0 .. NROWS*128-1
  const int r = idx & (NROWS - 1);
  const int c = idx >> 13;                          // kc 0..127
  const float4 v0 = *reinterpret_cast<const float4*>(X + (size_t)r * DIM + c * 8);
  const float4 v1 = *reinterpret_cast<const float4*>(X + (size_t)r * DIM + c * 8 + 4);
  const float f[8] = {v0.x, v0.y, v0.z, v0.w, v1.x, v1.y, v1.z, v1.w};
  u16x8 H, Lv;
#pragma unroll
  for (int e = 0; e < 8; ++e) {
    const u16 h = f2bf(f[e]);
    H[e]  = h;
    Lv[e] = f2bf(f[e] - bf2f(h));
  }
  const size_t dst = (size_t)c * (NROWS * 8) + (size_t)r * 8;
  *reinterpret_cast<u16x8*>(hi + dst) = H;
  *reinterpret_cast<u16x8*>(lo + dst) = Lv;
}

// ---------------------------------------------------------------------------
// Fused gather + split-GEMM, 2-phase dbuf with COUNTED vmcnt (T4):
//   prologue: STAGE(0), STAGE(1)            (16 loads in flight)
//   step t:   vmcnt(8) ; s_barrier          (oldest 8 landed -> buf ready)
//             COMPUTE(buf)
//             s_barrier ; STAGE(t+2 -> buf) (reads done -> safe to overwrite)
// No vmcnt(0) drain in the main loop: prefetch loads span a full step.
// ---------------------------------------------------------------------------
template <int WRITE_MODE>
__global__ __launch_bounds__(256, 2) void k_gemm(
    const u16* __restrict__ Xhi, const u16* __restrict__ Xlo,
    const u16* __restrict__ Whi, const u16* __restrict__ Wlo,
    const u16* __restrict__ oobhi, const u16* __restrict__ ooblo,
    const float* __restrict__ bias,
    float* __restrict__ outF, u16* __restrict__ outHi, u16* __restrict__ outLo,
    int delta) {
  __shared__ char smem[65536];   // 2 buffers x [Ah 8K][Al 8K][Bh 8K][Bl 8K]

  const int tid  = threadIdx.x;
  const int w    = tid >> 6;
  const int lane = tid & 63;
  const int wm = w >> 1, wn = w & 1;
  const int g4 = lane >> 4, i16 = lane & 15;

  // XCD row-band swizzle (bijective): xcd = L&7 owns by-band [8*xcd, 8*xcd+8).
  const int Lr  = blockIdx.y * 8 + blockIdx.x;
  const int xcd = Lr & 7, ii = Lr >> 3;
  const int bx  = ii & 7;
  const int by  = (xcd << 3) | (ii >> 3);

  const int mst = ((w & 1) << 6) | lane;   // staged row/col (kc=2j+(w>>1))
  const int kcw = w >> 1;

  const f32x4 zero = {0.f, 0.f, 0.f, 0.f};
  f32x4 acc[4][4];
#pragma unroll
  for (int a = 0; a < 4; ++a)
#pragma unroll
    for (int b = 0; b < 4; ++b) acc[a][b] = zero;

  const int bcol = bx * 128 + mst;
  const int grow = by * 128 + mst;

  const int fragA = g4 * 2048 + wm * 1024 + i16 * 16;
  const int fragB = g4 * 2048 + wn * 1024 + i16 * 16;

  // t in [0,96): s = t>>5 (segment), k0 = (t&31)*32
  auto STAGE = [&](int t, int bo) {
    const int s  = t >> 5;
    const int k0 = (t & 31) << 5;
    const int sr = (s == 0) ? grow : ((s == 1) ? grow - delta : grow + delta);
    const bool valid = (sr >= 0) && (sr < NROWS);
#pragma unroll
    for (int j = 0; j < 2; ++j) {
      const int ksrc = k0 + (2 * j + kcw) * 8;
      const int kk   = s * DIM + ksrc;
      const int loff = bo + j * 4096 + w * 1024;
      const size_t aoff = (size_t)(ksrc >> 3) * (NROWS * 8) + (size_t)sr * 8;
      gload16(valid ? (Xhi + aoff) : (oobhi + ksrc), smem + loff);
      gload16(valid ? (Xlo + aoff) : (ooblo + ksrc), smem + 8192 + loff);
      const size_t boff = (size_t)(kk >> 3) * (DIM * 8) + (size_t)bcol * 8;
      gload16(Whi + boff, smem + 16384 + loff);
      gload16(Wlo + boff, smem + 24576 + loff);
    }
  };

  auto COMPUTE = [&](int bo) {
    bf16x8 bh[4], bl[4];
#pragma unroll
    for (int fn = 0; fn < 4; ++fn) {
      bh[fn] = *(const bf16x8*)(smem + 16384 + bo + fragB + fn * 256);
      bl[fn] = *(const bf16x8*)(smem + 24576 + bo + fragB + fn * 256);
    }
#pragma unroll
    for (int fm = 0; fm < 4; ++fm) {
      const bf16x8 ah = *(const bf16x8*)(smem + bo + fragA + fm * 256);
      const bf16x8 al = *(const bf16x8*)(smem + 8192 + bo + fragA + fm * 256);
#pragma unroll
      for (int fn = 0; fn < 4; ++fn) {
        acc[fm][fn] = __builtin_amdgcn_mfma_f32_16x16x32_bf16(ah, bh[fn], acc[fm][fn], 0, 0, 0);
        acc[fm][fn] = __builtin_amdgcn_mfma_f32_16x16x32_bf16(ah, bl[fn], acc[fm][fn], 0, 0, 0);
        acc[fm][fn] = __builtin_amdgcn_mfma_f32_16x16x32_bf16(al, bh[fn], acc[fm][fn], 0, 0, 0);
      }
    }
  };

  STAGE(0, 0);
  STAGE(1, 32768);            // 16 loads in flight
  int bo = 0;
#pragma unroll 1
  for (int t = 0; t < 96; ++t) {
    if (t < 95) {
      asm volatile("s_waitcnt vmcnt(8)" ::: "memory");  // oldest 8 landed
    } else {
      asm volatile("s_waitcnt vmcnt(0)" ::: "memory");  // tail drain
    }
    __builtin_amdgcn_s_barrier();   // all waves certified their slice
    COMPUTE(bo);
    if (t < 94) {
      __builtin_amdgcn_s_barrier(); // all reads of buf done -> overwrite ok
      STAGE(t + 2, bo);
    }
    bo ^= 32768;
  }

  // epilogue: bias + relu + residual (exact reconstruct from split pair)
  const int col0 = bx * 128 + wn * 64;
  const int row0 = by * 128 + wm * 64;
#pragma unroll
  for (int fn = 0; fn < 4; ++fn) {
    const int col = col0 + fn * 16 + i16;
    const float bv = bias[col];
    const size_t cb = (size_t)(col >> 3) * (NROWS * 8) + (col & 7);
#pragma unroll
    for (int fm = 0; fm < 4; ++fm) {
      const int rbase = row0 + fm * 16 + g4 * 4;
#pragma unroll
      for (int r = 0; r < 4; ++r) {
        const int row = rbase + r;
        const size_t offB = cb + (size_t)row * 8;
        float v = acc[fm][fn][r] + bv;
        v = v > 0.f ? v : 0.f;
        const float res = bf2f(Xhi[offB]) + bf2f(Xlo[offB]);
        v = 0.5f * res + 0.5f * v;
        if (WRITE_MODE == 1) {
          outF[(size_t)row * DIM + col] = v;
        } else {
          const u16 h = f2bf(v);
          outHi[offB] = h;
          outLo[offB] = f2bf(v - bf2f(h));
        }
      }
    }
  }
}

// ---------------------------------------------------------------------------
extern "C" void kernel_launch(void* const* d_in, const int* in_sizes, int n_in,
                              void* d_out, int out_size, void* d_ws, size_t ws_size,
                              hipStream_t stream) {
  const float* X   = (const float*)d_in[0];
  const float* Ws  = (const float*)d_in[1];
  const float* bs  = (const float*)d_in[2];
  const float* oob = (const float*)d_in[3];

  char* ws = (char*)d_ws;
  u16* WThi = (u16*)ws;  ws += (size_t)NLAYERS * DIM * K3 * 2;   // 25,165,824 B
  u16* WTlo = (u16*)ws;  ws += (size_t)NLAYERS * DIM * K3 * 2;
  u16* Xh[2]; u16* Xl[2];
  Xh[0] = (u16*)ws;  ws += (size_t)NROWS * DIM * 2;              // 16,777,216 B
  Xl[0] = (u16*)ws;  ws += (size_t)NROWS * DIM * 2;
  Xh[1] = (u16*)ws;  ws += (size_t)NROWS * DIM * 2;
  Xl[1] = (u16*)ws;  ws += (size_t)NROWS * DIM * 2;
  u16* Ohi = (u16*)ws;  ws += 2048;
  u16* Olo = (u16*)ws;  ws += 2048;
  // total ~117.5 MB of d_ws

  k_prep_w<<<dim3(K3 * DIM / 8 / 256, NLAYERS), dim3(256), 0, stream>>>(Ws, WThi, WTlo);
  k_oob<<<dim3(4), dim3(256), 0, stream>>>(oob, Ohi, Olo);
  k_split<<<dim3(NROWS * (DIM / 8) / 256), dim3(256), 0, stream>>>(X, Xh[0], Xl[0]);

  const int deltas[NLAYERS] = {1, 2, 4, 1};
  int cur = 0;
  for (int i = 0; i < NLAYERS; ++i) {
    const u16* whi = WThi + (size_t)i * DIM * K3;
    const u16* wlo = WTlo + (size_t)i * DIM * K3;
    const float* bi = bs + (size_t)i * DIM;
    if (i < NLAYERS - 1) {
      k_gemm<0><<<dim3(DIM / 128, NROWS / 128), dim3(256), 0, stream>>>(
          Xh[cur], Xl[cur], whi, wlo, Ohi, Olo, bi,
          nullptr, Xh[cur ^ 1], Xl[cur ^ 1], deltas[i]);
    } else {
      k_gemm<1><<<dim3(DIM / 128, NROWS / 128), dim3(256), 0, stream>>>(
          Xh[cur], Xl[cur], whi, wlo, Ohi, Olo, bi,
          (float*)d_out, nullptr, nullptr, deltas[i]);
    }
    cur ^= 1;
  }
}